// Round 2
// baseline (3315.584 us; speedup 1.0000x reference)
//
#include <hip/hip_runtime.h>
#include <stdint.h>

// ---------------------------------------------------------------------------
// 2-layer GRU, B=128, T=1024, H=IN=256, OUT=128.  Dtype probed on device.
//
// v7b: resubmission of v7 (round-1 bench died to container/infra failure,
// no counters).  Same 4-stage relaxed-sc1 spin-pipeline and ring layout as
// v6 (256 blocks, roles L0X/L0H/L1X/L1H x 64 batch-pairs, weights
// register-resident, one barrier/step, in-band 8B {payload,tag} atomics).
// Changes vs v6, one theory ("cut per-step VALU issue + unhidden store
// drains"):
//  1) 1024 threads/block, K split 4-way (p=tid>>2, ks=tid&3): per-thread
//     weights drop 192->96 dwords, fitting the 128-reg budget at 4
//     waves/SIMD -> eliminates the v_accvgpr_read storm (v6: VGPR_Count
//     still 128, most weights AGPR-resident, ~2.5x VALU per dot).
//     4-lane __shfl_xor reduction replaces the 2-lane one.
//  2) lgkm-only barrier: __syncthreads emits s_waitcnt vmcnt(0) which
//     synchronously drains the ring-publish atomic every step (~500-900cy
//     MALL round trip).  Only LDS ordering is needed (rings are
//     tag-spin-protected) -> asm lgkmcnt(0) + raw s_barrier.
//  3) v_rcp_f32 instead of full-precision divides in sigmoid/tanh.
//  v7b hardening: amdgpu_waves_per_eu(4) min-only (same 128-VGPR cap,
//  less allocator constraint than (4,4)).
//  LDS skew: +4 dwords per 32 so the 4 K-quarters (dword offsets
//  0/36/72/108) hit disjoint bank groups on ds_read_b128.
// ---------------------------------------------------------------------------

#define NPAIR 64

// ws layout in dwords (unchanged from v6)
#define XR0_OFF 0            // uint2 [64][4][512]  (262144 dw)
#define XR1_OFF 262144       // uint2 [64][4][512]
#define HR0_OFF 524288       // uint2 [64][4][256]  (131072 dw)
#define CTR_OFF 655360       // u32   [4][64][16]
#define FLG_OFF 659456

#if defined(__has_builtin)
#if __has_builtin(__builtin_amdgcn_fdot2)
#define USE_DOT2 1
#endif
#if __has_builtin(__builtin_amdgcn_rcpf)
#define USE_RCP 1
#endif
#endif

typedef uint32_t u32x16 __attribute__((ext_vector_type(16)));
typedef _Float16 h2_t __attribute__((ext_vector_type(2)));
union H2U { uint32_t u; h2_t h; };
union FU  { uint32_t u; float f; };

__device__ __forceinline__ float bf2f(uint16_t b){ FU v; v.u=(uint32_t)b<<16; return v.f; }
__device__ __forceinline__ uint16_t f2bf(float f){
    FU v; v.f=f; uint32_t r=v.u+0x7fffu+((v.u>>16)&1u); return (uint16_t)(r>>16);
}
__device__ __forceinline__ float rcp_f(float x){
#ifdef USE_RCP
    return __builtin_amdgcn_rcpf(x);
#else
    return 1.0f/x;
#endif
}
__device__ __forceinline__ float sigmoid_f(float x){ return rcp_f(1.0f+__expf(-x)); }
__device__ __forceinline__ float tanh_f(float x){
    float ax=fabsf(x); float e=__expf(-2.0f*ax);
    float t=(1.0f-e)*rcp_f(1.0f+e); return x<0.0f?-t:t;
}
__device__ __forceinline__ float dot2acc(uint32_t w, uint32_t v, float acc){
#ifdef USE_DOT2
    H2U a,b; a.u=w; b.u=v;
    return __builtin_amdgcn_fdot2(a.h, b.h, acc, false);
#else
    FU x0,x1,y0,y1;
    x0.u=w<<16; x1.u=w&0xffff0000u; y0.u=v<<16; y1.u=v&0xffff0000u;
    acc=fmaf(x0.f,y0.f,acc); return fmaf(x1.f,y1.f,acc);
#endif
}
__device__ __forceinline__ uint32_t cvt_bfpair(uint32_t raw){
#ifdef USE_DOT2
    FU lo,hi; lo.u=raw<<16; hi.u=raw&0xffff0000u;
    H2U r; r.h[0]=(_Float16)lo.f; r.h[1]=(_Float16)hi.f; return r.u;
#else
    return raw;
#endif
}
__device__ __forceinline__ uint32_t packpair(float lo, float hi){
#ifdef USE_DOT2
    H2U r; r.h[0]=(_Float16)lo; r.h[1]=(_Float16)hi; return r.u;
#else
    return (uint32_t)f2bf(lo) | ((uint32_t)f2bf(hi)<<16);
#endif
}
__device__ __forceinline__ u32x16 load16_bf(const uint4* p){
    uint4 a=p[0], b=p[1], c=p[2], d=p[3];
    u32x16 v;
    v[0]=cvt_bfpair(a.x);  v[1]=cvt_bfpair(a.y);  v[2]=cvt_bfpair(a.z);  v[3]=cvt_bfpair(a.w);
    v[4]=cvt_bfpair(b.x);  v[5]=cvt_bfpair(b.y);  v[6]=cvt_bfpair(b.z);  v[7]=cvt_bfpair(b.w);
    v[8]=cvt_bfpair(c.x);  v[9]=cvt_bfpair(c.y);  v[10]=cvt_bfpair(c.z); v[11]=cvt_bfpair(c.w);
    v[12]=cvt_bfpair(d.x); v[13]=cvt_bfpair(d.y); v[14]=cvt_bfpair(d.z); v[15]=cvt_bfpair(d.w);
    return v;
}
__device__ __forceinline__ u32x16 load16_f32(const float2* p){
    u32x16 v;
#define LF(i) v[i] = packpair(p[i].x, p[i].y)
    LF(0);LF(1);LF(2);LF(3);LF(4);LF(5);LF(6);LF(7);
    LF(8);LF(9);LF(10);LF(11);LF(12);LF(13);LF(14);LF(15);
#undef LF
    return v;
}

#define RLX_LD(p)    __hip_atomic_load((p),        __ATOMIC_RELAXED, __HIP_MEMORY_SCOPE_AGENT)
#define RLX_ST(p,v)  __hip_atomic_store((p), (v),  __ATOMIC_RELAXED, __HIP_MEMORY_SCOPE_AGENT)
__device__ __forceinline__ uint64_t RLX_LD64(const uint64_t* p){
    return __hip_atomic_load(p, __ATOMIC_RELAXED, __HIP_MEMORY_SCOPE_AGENT);
}
__device__ __forceinline__ void RLX_ST64(uint64_t* p, uint64_t v){
    __hip_atomic_store(p, v, __ATOMIC_RELAXED, __HIP_MEMORY_SCOPE_AGENT);
}

// LDS-only barrier: order LDS (lgkmcnt) but do NOT drain vmcnt -> the 8B
// ring-publish atomics keep draining under the next dot loop.  The
// "memory"-clobber asms pin all memory ops on both sides of s_barrier.
#define BAR() do {                                              \
    asm volatile("s_waitcnt lgkmcnt(0)" ::: "memory");          \
    __builtin_amdgcn_s_barrier();                               \
    asm volatile("" ::: "memory");                              \
} while (0)

// 16 dwords of input (one half of this lane's K-quarter) vs 3 weight vecs
#define DOT16(WR, WZ, WN, G)                                                      \
    _Pragma("unroll")                                                             \
    for (int q = 0; q < 4; ++q) {                                                 \
        uint4 va = pa[4*(G)+q], vb = pb[4*(G)+q];                                 \
        ar0 = dot2acc(WR[4*q+0], va.x, ar0); ar1 = dot2acc(WR[4*q+0], vb.x, ar1); \
        az0 = dot2acc(WZ[4*q+0], va.x, az0); az1 = dot2acc(WZ[4*q+0], vb.x, az1); \
        an0 = dot2acc(WN[4*q+0], va.x, an0); an1 = dot2acc(WN[4*q+0], vb.x, an1); \
        ar0 = dot2acc(WR[4*q+1], va.y, ar0); ar1 = dot2acc(WR[4*q+1], vb.y, ar1); \
        az0 = dot2acc(WZ[4*q+1], va.y, az0); az1 = dot2acc(WZ[4*q+1], vb.y, az1); \
        an0 = dot2acc(WN[4*q+1], va.y, an0); an1 = dot2acc(WN[4*q+1], vb.y, an1); \
        ar0 = dot2acc(WR[4*q+2], va.z, ar0); ar1 = dot2acc(WR[4*q+2], vb.z, ar1); \
        az0 = dot2acc(WZ[4*q+2], va.z, az0); az1 = dot2acc(WZ[4*q+2], vb.z, az1); \
        an0 = dot2acc(WN[4*q+2], va.z, an0); an1 = dot2acc(WN[4*q+2], vb.z, an1); \
        ar0 = dot2acc(WR[4*q+3], va.w, ar0); ar1 = dot2acc(WR[4*q+3], vb.w, ar1); \
        az0 = dot2acc(WZ[4*q+3], va.w, az0); az1 = dot2acc(WZ[4*q+3], vb.w, az1); \
        an0 = dot2acc(WN[4*q+3], va.w, an0); an1 = dot2acc(WN[4*q+3], vb.w, an1); \
    }

__global__ void probe_init(const uint32_t* __restrict__ w,
                           uint32_t* __restrict__ ctr,
                           uint32_t* __restrict__ flag) {
    int i = threadIdx.x;
    for (int k = i; k < 4096; k += 1024) ctr[k] = 0u;
    if (i == 0) {
        int c = 0;
        for (int j = 0; j < 64; ++j) {
            uint32_t e = (w[j] >> 7) & 0xFFu;
            c += (e >= 0x60u && e <= 0x7Cu) ? 1 : 0;
        }
        flag[0] = (c >= 32) ? 1u : 0u;
    }
}

__global__ void __launch_bounds__(1024) __attribute__((amdgpu_waves_per_eu(4)))
gru8(const void* __restrict__ xin,
     const void* __restrict__ Wx0, const void* __restrict__ bx0,
     const void* __restrict__ Wh0, const void* __restrict__ bh0,
     const void* __restrict__ Wx1, const void* __restrict__ bx1,
     const void* __restrict__ Wh1, const void* __restrict__ bh1,
     const void* __restrict__ Wo,  const void* __restrict__ bo,
     void* __restrict__ out,
     uint32_t* __restrict__ ws)
{
    const int tid  = threadIdx.x;
    const int pair = blockIdx.x & (NPAIR - 1);
    const int role = blockIdx.x >> 6;
    const int p    = tid >> 2;       // hidden unit / row base (0..255)
    const int ks   = tid & 3;        // K-quarter (64 elems = 32 dwords)

    uint64_t* XR0p = (uint64_t*)(ws + XR0_OFF) + pair * 2048;   // 4 slots x 512
    uint64_t* XR1p = (uint64_t*)(ws + XR1_OFF) + pair * 2048;
    uint64_t* HRp  = (uint64_t*)(ws + HR0_OFF) + pair * 1024;   // 4 slots x 256
    uint32_t* CTR  = ws + CTR_OFF;
    const int isbf = (int)ws[FLG_OFF];

    uint32_t* myprg   = CTR + role * 1024 + pair * 16;          // my staged step
    uint32_t* consprg = CTR + (role + 1) * 1024 + pair * 16;    // downstream's

    const void* Wsel; const void* bsel;
    if      (role == 0) { Wsel = Wx0; bsel = bx0; }
    else if (role == 1) { Wsel = Wh0; bsel = bh0; }
    else if (role == 2) { Wsel = Wx1; bsel = bx1; }
    else                { Wsel = Wh1; bsel = bh1; }

    // 6 named SSA weight vectors: K-quarter ks of rows {p, p+256, p+512}
    u32x16 wr0,wr1, wz0,wz1, wn0,wn1;
    float br, bz, bn;
    if (isbf) {
        const uint4* W4 = (const uint4*)Wsel;
        const uint4* r0 = W4 + (size_t)p * 32 + ks * 8;
        const uint4* r1 = W4 + (size_t)(p + 256) * 32 + ks * 8;
        const uint4* r2 = W4 + (size_t)(p + 512) * 32 + ks * 8;
        wr0=load16_bf(r0);   wr1=load16_bf(r0+4);
        wz0=load16_bf(r1);   wz1=load16_bf(r1+4);
        wn0=load16_bf(r2);   wn1=load16_bf(r2+4);
        const uint16_t* bs = (const uint16_t*)bsel;
        br = bf2f(bs[p]); bz = bf2f(bs[p+256]); bn = bf2f(bs[p+512]);
    } else {
        const float2* W2 = (const float2*)Wsel;
        const float2* r0 = W2 + (size_t)p * 128 + ks * 32;
        const float2* r1 = W2 + (size_t)(p + 256) * 128 + ks * 32;
        const float2* r2 = W2 + (size_t)(p + 512) * 128 + ks * 32;
        wr0=load16_f32(r0);   wr1=load16_f32(r0+16);
        wz0=load16_f32(r1);   wz1=load16_f32(r1+16);
        wn0=load16_f32(r2);   wn1=load16_f32(r2+16);
        const float* bs = (const float*)bsel;
        br = bs[p]; bz = bs[p+256]; bn = bs[p+512];
    }

    // skewed LDS: 2 buffers x (2 x 144-dw batch halves); +4-dw pad per 32
    // so the 4 K-quarters (offsets 0/36/72/108 dw) hit disjoint bank groups
    __shared__ __align__(16) uint32_t sb[576];

    if (role == 0 || role == 2) {
        // ------------------------------ X stages ---------------------------
        const uint32_t* xs32 = (const uint32_t*)xin;
        const float2*   xsf  = (const float2*)xin;
        const int bglob = pair * 2 + (tid >> 7);
        const int i128  = tid & 127;
        const int spos  = (tid >> 7) * 144 + i128 + ((i128 >> 5) << 2);
        uint32_t xpref = 0;
        uint2 pfh; pfh.x = 0; pfh.y = 0;
        if (role == 0 && tid < 256) {
            if (isbf) xpref = cvt_bfpair(xs32[(size_t)bglob * 131072 + i128]);
            else { float2 f = xsf[(size_t)bglob * 131072 + i128]; xpref = packpair(f.x, f.y); }
        }
        uint64_t* outring = (role == 0) ? XR0p : XR1p;
        uint32_t prog_seen = 0;

        for (int t = 0; t < 1024; ++t) {
            if (t >= 4 && prog_seen + 3 < (uint32_t)t) {     // ring-wrap guard
                do { prog_seen = RLX_LD(consprg);
                     if (prog_seen + 3 < (uint32_t)t) __builtin_amdgcn_s_sleep(2);
                } while (prog_seen + 3 < (uint32_t)t);
            }
            if (tid < 256) {
                uint32_t pk;
                if (role == 0) pk = xpref;
                else {
                    uint2 v = pfh;
                    const uint32_t want = (uint32_t)(t + 1);
                    if (v.y != want) {
                        const uint64_t* a = HRp + (t & 3) * 256 + tid;
                        uint64_t u;
                        do { u = RLX_LD64(a);
                             v.x = (uint32_t)u; v.y = (uint32_t)(u >> 32);
                             if (v.y != want) __builtin_amdgcn_s_sleep(1);
                        } while (v.y != want);
                    }
                    pk = v.x;
                }
                sb[(t & 1) * 288 + spos] = pk;
            }
            BAR();
            if (tid == 0 && !(t & 1)) RLX_ST(myprg, (uint32_t)t);
            if (tid < 256 && t < 1023) {                     // prefetch t+1
                if (role == 0) {
                    if (isbf) xpref = cvt_bfpair(xs32[(size_t)bglob * 131072 + (t+1)*128 + i128]);
                    else { float2 f = xsf[(size_t)bglob * 131072 + (t+1)*128 + i128]; xpref = packpair(f.x, f.y); }
                } else {
                    uint64_t u = RLX_LD64(HRp + ((t + 1) & 3) * 256 + tid);
                    pfh.x = (uint32_t)u; pfh.y = (uint32_t)(u >> 32);
                }
            }
            float ar0=0,ar1=0,az0=0,az1=0,an0=0,an1=0;
            {
                const uint4* pa = ((const uint4*)sb) + (t & 1) * 72 + ks * 9;
                const uint4* pb = pa + 36;
                DOT16(wr0,wz0,wn0,0); DOT16(wr1,wz1,wn1,1);
            }
            float s;
            s = ar0 + __shfl_xor(ar0,1); float R0 = s + __shfl_xor(s,2);
            s = ar1 + __shfl_xor(ar1,1); float R1 = s + __shfl_xor(s,2);
            s = az0 + __shfl_xor(az0,1); float Z0 = s + __shfl_xor(s,2);
            s = az1 + __shfl_xor(az1,1); float Z1 = s + __shfl_xor(s,2);
            s = an0 + __shfl_xor(an0,1); float N0 = s + __shfl_xor(s,2);
            s = an1 + __shfl_xor(an1,1); float N1 = s + __shfl_xor(s,2);
            if (ks < 2) {
                float sr = (ks ? R1 : R0) + br;
                float sz = (ks ? Z1 : Z0) + bz;
                float sn = (ks ? N1 : N0) + bn;
                // publish {f16 sr, f16 sz | f16 sn, tag16} as one 8B atomic
                H2U lo; lo.h[0] = (_Float16)sr; lo.h[1] = (_Float16)sz;
                H2U sn16; sn16.u = 0; sn16.h[0] = (_Float16)sn;
                uint32_t hi = (sn16.u & 0xFFFFu) | (((uint32_t)(t + 1)) << 16);
                RLX_ST64(outring + (t & 3) * 512 + 2 * p + ks,
                         (uint64_t)lo.u | ((uint64_t)hi << 32));
            }
        }
    } else {
        // ------------------------------ H stages ---------------------------
        const uint64_t* xr64 = (role == 1) ? XR0p : XR1p;
        float h_reg = 0.0f;
        for (int i = tid; i < 576; i += 1024) sb[i] = 0u;   // h(0) = 0
        uint2 pfx; pfx.x = 0; pfx.y = 0;
        uint32_t prog_seen = 0;
        const int b     = ks & 1;                 // this lane's batch
        const int hj    = tid >> 3;               // p >> 1
        const int hpos  = b * 144 + hj + ((hj >> 5) << 2);
        const int wlane = !(tid & 6);             // p even, ks in {0,1}

        for (int t = 0; t < 1024; ++t) {
            if (role == 1 && t >= 4 && prog_seen + 3 < (uint32_t)t) {
                do { prog_seen = RLX_LD(consprg);
                     if (prog_seen + 3 < (uint32_t)t) __builtin_amdgcn_s_sleep(2);
                } while (prog_seen + 3 < (uint32_t)t);
            }
            uint2 v = pfx;
            const uint32_t want = (uint32_t)(t + 1);
            if ((v.y >> 16) != want) {
                const uint64_t* a = xr64 + (t & 3) * 512 + 2 * p + b;
                uint64_t u;
                do { u = RLX_LD64(a);
                     v.x = (uint32_t)u; v.y = (uint32_t)(u >> 32);
                     if ((v.y >> 16) != want) __builtin_amdgcn_s_sleep(1);
                } while ((v.y >> 16) != want);
            }
            H2U ua; ua.u = v.x;
            H2U ub; ub.u = v.y & 0xFFFFu;
            float xr = (float)ua.h[0], xz = (float)ua.h[1], xn = (float)ub.h[0];
            BAR();                           // h(t) LDS writes (prev iter) visible
            if (tid == 0 && !(t & 1)) RLX_ST(myprg, (uint32_t)t);
            if (t < 1023) {                  // prefetch t+1
                uint64_t u = RLX_LD64(xr64 + ((t + 1) & 3) * 512 + 2 * p + b);
                pfx.x = (uint32_t)u; pfx.y = (uint32_t)(u >> 32);
            }
            float ar0=0,ar1=0,az0=0,az1=0,an0=0,an1=0;
            {
                const uint4* pa = ((const uint4*)sb) + (t & 1) * 72 + ks * 9;
                const uint4* pb = pa + 36;
                DOT16(wr0,wz0,wn0,0); DOT16(wr1,wz1,wn1,1);
            }
            float s;
            s = ar0 + __shfl_xor(ar0,1); float R0 = s + __shfl_xor(s,2);
            s = ar1 + __shfl_xor(ar1,1); float R1 = s + __shfl_xor(s,2);
            s = az0 + __shfl_xor(az0,1); float Z0 = s + __shfl_xor(s,2);
            s = az1 + __shfl_xor(az1,1); float Z1 = s + __shfl_xor(s,2);
            s = an0 + __shfl_xor(an0,1); float N0 = s + __shfl_xor(s,2);
            s = an1 + __shfl_xor(an1,1); float N1 = s + __shfl_xor(s,2);
            float r = sigmoid_f(xr + (b ? R1 : R0) + br);
            float z = sigmoid_f(xz + (b ? Z1 : Z0) + bz);
            float n = tanh_f(xn + r * ((b ? N1 : N0) + bn));
            h_reg = z * h_reg + (1.0f - z) * n;     // h[p], batch b
            float hp = __shfl_xor(h_reg, 4);        // h[p^1], batch b
            if (wlane) {                            // p even: pack (h[p],h[p+1])
                uint32_t pk = packpair(h_reg, hp);
                sb[((t + 1) & 1) * 288 + hpos] = pk;
                if (role == 1)
                    RLX_ST64(HRp + (t & 3) * 256 + b * 128 + hj,
                             (uint64_t)pk | ((uint64_t)(t + 1) << 32));
            }
        }
        BAR();
        if (tid == 0) RLX_ST(myprg, 1024u);

        // ---------------- epilogue (role 3): out = h1.Wo^T + bo ------------
        if (role == 3 && tid < 256) {
            const int j = tid >> 1, bb = tid & 1;
            const uint32_t* hv = &sb[bb * 144];     // final h1 in buffer 0
            float acc;
            if (isbf) {
                acc = bf2f(((const uint16_t*)bo)[j]);
                const uint32_t* wo = (const uint32_t*)Wo + j * 128;
#pragma unroll 8
                for (int c = 0; c < 128; ++c)
                    acc = dot2acc(cvt_bfpair(wo[c]), hv[c + ((c >> 5) << 2)], acc);
                ((uint16_t*)out)[(pair * 2 + bb) * 128 + j] = f2bf(acc);
            } else {
                acc = ((const float*)bo)[j];
                const float2* wo = (const float2*)Wo + j * 128;
#pragma unroll 8
                for (int c = 0; c < 128; ++c) {
                    float2 f = wo[c];
                    acc = dot2acc(packpair(f.x, f.y), hv[c + ((c >> 5) << 2)], acc);
                }
                ((float*)out)[(pair * 2 + bb) * 128 + j] = acc;
            }
        }
    }
}

extern "C" void kernel_launch(void* const* d_in, const int* in_sizes, int n_in,
                              void* d_out, int out_size, void* d_ws, size_t ws_size,
                              hipStream_t stream) {
    uint32_t* ws  = (uint32_t*)d_ws;
    uint32_t* CTR = ws + CTR_OFF;
    uint32_t* FLG = ws + FLG_OFF;

    probe_init<<<dim3(1), dim3(1024), 0, stream>>>((const uint32_t*)d_in[1], CTR, FLG);
    gru8<<<dim3(256), dim3(1024), 0, stream>>>(
        d_in[0], d_in[1], d_in[2], d_in[3], d_in[4],
        d_in[5], d_in[6], d_in[7], d_in[8], d_in[9], d_in[10],
        d_out, ws);
}